// Round 8
// baseline (207.148 us; speedup 1.0000x reference)
//
#include <hip/hip_runtime.h>
#include <hip/hip_bf16.h>
#include <hip/hip_fp16.h>
#include <math.h>

#define B 8
#define C 256
#define HH 64
#define WW 64
#define NN 4096      // H*W
#define CI 128
#define NS 1024      // pooled spatial
#define EPS 1e-5f
#define THR 8.0f

typedef __attribute__((ext_vector_type(8))) _Float16 f16x8;
typedef __attribute__((ext_vector_type(4))) float f32x4;
typedef __attribute__((ext_vector_type(16))) float f32x16;

static __device__ __forceinline__ unsigned short f2h_bits(float f) {
    return __half_as_ushort(__float2half(f));   // v_cvt_f16_f32 (RNE)
}
static __device__ __forceinline__ float h2f(unsigned short u) {
    return __half2float(__ushort_as_half(u));
}
static __device__ __forceinline__ unsigned pk2(float a, float b) {
    typedef __fp16 fp16x2_t __attribute__((ext_vector_type(2)));
    union { fp16x2_t h; unsigned u; } cv;
    cv.h = __builtin_amdgcn_cvt_pkrtz(a, b);
    return cv.u;
}

// ---------------------------------------------------------------- K0: x transpose->f16 (+ weight prep folded in)
__global__ __launch_bounds__(256) void k_xt(const float* __restrict__ x,
        unsigned short* __restrict__ xh,
        const float* __restrict__ tw, const float* __restrict__ pw,
        const float* __restrict__ gw, const float* __restrict__ ww,
        unsigned short* __restrict__ wh) {
    int tid = threadIdx.x;
    if (blockIdx.x == 64) {   // weight prep: 32 instances x 4096 elements
        int inst = blockIdx.y * B + blockIdx.z;       // 0..31
        int base = inst * 4096;
        #pragma unroll
        for (int k = 0; k < 16; ++k) {
            int idx = base + tid + k * 256;           // 0..131071
            int sel = idx >> 15, off = idx & 32767;
            const float* src = (sel == 0) ? tw : (sel == 1) ? pw : (sel == 2) ? gw : ww;
            wh[idx] = f2h_bits(src[off]);
        }
        return;
    }
    __shared__ float s_t[64 * 65];
    int n0 = blockIdx.x * 64;
    int c0 = blockIdx.y * 64;
    int b  = blockIdx.z;
    #pragma unroll
    for (int k = 0; k < 16; ++k) {
        int idx = tid + k * 256;           // 0..4095
        int cl = idx >> 6, nl = idx & 63;
        s_t[cl * 65 + nl] = x[((size_t)b * C + c0 + cl) * NN + n0 + nl];
    }
    __syncthreads();
    #pragma unroll
    for (int k = 0; k < 8; ++k) {
        int idx = tid + k * 256;           // 0..2047
        int nl = idx >> 5, cp = (idx & 31) * 2;
        ushort2 o;
        o.x = f2h_bits(s_t[cp * 65 + nl]);
        o.y = f2h_bits(s_t[(cp + 1) * 65 + nl]);
        *(ushort2*)&xh[((size_t)b * NN + n0 + nl) * C + c0 + cp] = o;
    }
}

// ---------------------------------------------------------------- K1: fused theta + pooled phi/g convs (MFMA)
__global__ __launch_bounds__(512) void k_convs(const unsigned short* __restrict__ xh,
        const unsigned short* __restrict__ twh, const unsigned short* __restrict__ pwh,
        const unsigned short* __restrict__ gwh,
        const float* __restrict__ tb, const float* __restrict__ pb, const float* __restrict__ gb_,
        unsigned short* __restrict__ theta, unsigned short* __restrict__ phi,
        unsigned short* __restrict__ gout) {
    int blk = blockIdx.x;                 // 256 blocks
    int b   = blk >> 5;
    int mh  = blk & 31;                   // pooled h row
    int tid = threadIdx.x;
    int lane = tid & 63, wv = tid >> 6;
    int lr = lane & 15, lh = lane >> 4;
    int wn = wv & 3, wc = wv >> 2;
    size_t row0 = (size_t)blk * 128;

    f32x4 accT[8];
    f32x4 aP0[4], aP1[4], aG0[4], aG1[4];
    #pragma unroll
    for (int i = 0; i < 8; ++i) accT[i] = (f32x4){0,0,0,0};
    #pragma unroll
    for (int i = 0; i < 4; ++i) {
        aP0[i] = (f32x4){0,0,0,0}; aP1[i] = (f32x4){0,0,0,0};
        aG0[i] = (f32x4){0,0,0,0}; aG1[i] = (f32x4){0,0,0,0};
    }

    const unsigned short* ap0 = xh + (row0 + wn * 16 + lr) * C + lh * 8;
    const unsigned short* ap1 = ap0 + (size_t)64 * C;
    #pragma unroll
    for (int kc = 0; kc < 8; ++kc) {
        f16x8 a0 = *(const f16x8*)(ap0 + kc * 32);
        f16x8 a1 = *(const f16x8*)(ap1 + kc * 32);
        f16x8 aT = (wv < 4) ? a0 : a1;
        #pragma unroll
        for (int ct = 0; ct < 8; ++ct) {
            f16x8 bt_ = *(const f16x8*)&twh[(ct * 16 + lr) * C + kc * 32 + lh * 8];
            accT[ct] = __builtin_amdgcn_mfma_f32_16x16x32_f16(aT, bt_, accT[ct], 0, 0, 0);
        }
        #pragma unroll
        for (int ct = 0; ct < 4; ++ct) {
            int wrow = (wc * 64 + ct * 16 + lr) * C + kc * 32 + lh * 8;
            f16x8 bp = *(const f16x8*)&pwh[wrow];
            f16x8 bg = *(const f16x8*)&gwh[wrow];
            aP0[ct] = __builtin_amdgcn_mfma_f32_16x16x32_f16(a0, bp, aP0[ct], 0, 0, 0);
            aP1[ct] = __builtin_amdgcn_mfma_f32_16x16x32_f16(a1, bp, aP1[ct], 0, 0, 0);
            aG0[ct] = __builtin_amdgcn_mfma_f32_16x16x32_f16(a0, bg, aG0[ct], 0, 0, 0);
            aG1[ct] = __builtin_amdgcn_mfma_f32_16x16x32_f16(a1, bg, aG1[ct], 0, 0, 0);
        }
    }
    #pragma unroll
    for (int ct = 0; ct < 8; ++ct) {
        int ci = ct * 16 + lr;
        float bias = tb[ci];
        #pragma unroll
        for (int r = 0; r < 4; ++r)
            theta[(row0 + wv * 16 + lh * 4 + r) * CI + ci] = f2h_bits(accT[ct][r] + bias);
    }
    #pragma unroll
    for (int ct = 0; ct < 4; ++ct) {
        int ci = wc * 64 + ct * 16 + lr;
        float biasP = pb[ci], biasG = gb_[ci];
        #pragma unroll
        for (int j = 0; j < 2; ++j) {
            int m = mh * 32 + wn * 8 + lh * 2 + j;
            float vP = fmaxf(fmaxf(aP0[ct][2*j], aP0[ct][2*j+1]),
                             fmaxf(aP1[ct][2*j], aP1[ct][2*j+1])) + biasP;
            float vG = fmaxf(fmaxf(aG0[ct][2*j], aG0[ct][2*j+1]),
                             fmaxf(aG1[ct][2*j], aG1[ct][2*j+1])) + biasG;
            phi[((size_t)b * NS + m) * CI + ci]  = f2h_bits(vP);
            gout[((size_t)b * CI + ci) * NS + m] = f2h_bits(vG);
        }
    }
}

// ---------------------------------------------------------------- K3: fused attention v3
// 32x32x16 MFMA, swapped QK (A=phi, B=theta) -> in-register softmax; m-split x2 in block;
// XOR-swizzled zero-pad LDS; defer-rescale THR=8; in-block flash combine.
// theta [b][n][ci] f16, phi [b][m][ci] f16, g [b][ci][m] f16 -> y [b][n][ci] f16
__global__ __launch_bounds__(256) void k_attn_mfma(const unsigned short* __restrict__ theta,
        const unsigned short* __restrict__ phi, const unsigned short* __restrict__ g,
        unsigned short* __restrict__ y) {
    __shared__ unsigned lds_u32[20480];   // 81920 B exactly -> 2 blocks/CU
    int bid = blockIdx.x;                  // 512
    int b   = bid & 7;                     // batch -> XCD (round-robin heuristic)
    int rb  = bid >> 3;                    // 0..63
    int tid = threadIdx.x;
    int lane = tid & 63;
    int wv  = tid >> 6;
    int h   = wv & 1;                      // n-half (32 rows)
    int s   = wv >> 1;                     // m-half (8 tiles)
    int l31 = lane & 31;
    int lh2 = lane >> 5;                   // 0/1 (k-group)
    int xr  = (lane & 7) << 2;             // XOR swizzle (dwords)
    int row0 = rb * 64;

    const unsigned phb = s * 4096;           // phi stream base (dwords): 64 rows x 64 dw
    const unsigned gbb = 8192 + s * 4096;    // g stream base: 128 rows x 32 dw
    const unsigned pbb = 16384 + wv * 1024;  // P wave base: 32 rows x 32 dw

    // theta B-frags (col n = l31, k = lh2*8+j), held whole kernel
    f16x8 b_th[8];
    {
        const unsigned short* tp = theta + ((size_t)b * NN + row0 + h * 32 + l31) * CI + lh2 * 8;
        #pragma unroll
        for (int kc = 0; kc < 8; ++kc)
            b_th[kc] = *(const f16x8*)(tp + kc * 16);
    }

    const unsigned short* phsrc = phi + (size_t)b * NS * CI;
    const unsigned short* gsrc  = g + (size_t)b * CI * NS;
    int tl = tid & 127;                    // thread-in-stream

    uint4 rph[8], rg[8];
    auto issue = [&](int mt) {
        #pragma unroll
        for (int k = 0; k < 8; ++k) {
            int rowm = k * 8 + (tl >> 4);
            rph[k] = *(const uint4*)(phsrc + (size_t)(mt * 64 + rowm) * CI + (tl & 15) * 8);
            int ci = k * 16 + (tl >> 3);
            rg[k]  = *(const uint4*)(gsrc + (size_t)ci * NS + mt * 64 + (tl & 7) * 8);
        }
    };
    auto commit = [&]() {
        #pragma unroll
        for (int k = 0; k < 8; ++k) {
            int rowm = k * 8 + (tl >> 4);
            *(uint4*)&lds_u32[phb + rowm * 64 + (((tl & 15) * 4) ^ ((rowm & 7) << 2))] = rph[k];
            int ci = k * 16 + (tl >> 3);
            *(uint4*)&lds_u32[gbb + ci * 32 + (((tl & 7) * 4) ^ ((ci & 7) << 2))] = rg[k];
        }
    };

    f32x16 yacc[4];
    #pragma unroll
    for (int cc = 0; cc < 4; ++cc)
        #pragma unroll
        for (int i = 0; i < 16; ++i) yacc[cc][i] = 0.f;
    float mrun = -1e30f, lrun = 0.f;

    issue(s * 8);
    commit();
    __syncthreads();

    for (int step = 0; step < 8; ++step) {
        if (step < 7) issue(s * 8 + step + 1);

        // ---- S^T = phi * theta^T : lane holds 32 m-values for ONE n = l31
        f32x16 S0, S1;
        #pragma unroll
        for (int i = 0; i < 16; ++i) { S0[i] = 0.f; S1[i] = 0.f; }
        __builtin_amdgcn_s_setprio(1);
        #pragma unroll
        for (int kc = 0; kc < 8; ++kc) {
            unsigned dc = (unsigned)((kc * 8 + lh2 * 4) ^ xr);
            f16x8 a0 = *(const f16x8*)&lds_u32[phb + l31 * 64 + dc];
            f16x8 a1 = *(const f16x8*)&lds_u32[phb + (32 + l31) * 64 + dc];
            S0 = __builtin_amdgcn_mfma_f32_32x32x16_f16(a0, b_th[kc], S0, 0, 0, 0);
            S1 = __builtin_amdgcn_mfma_f32_32x32x16_f16(a1, b_th[kc], S1, 0, 0, 0);
        }
        __builtin_amdgcn_s_setprio(0);

        // ---- softmax: in-register over 32 values + one cross-half shuffle
        float tmax = S0[0];
        #pragma unroll
        for (int i = 1; i < 16; ++i) tmax = fmaxf(tmax, S0[i]);
        #pragma unroll
        for (int i = 0; i < 16; ++i) tmax = fmaxf(tmax, S1[i]);
        tmax = fmaxf(tmax, __shfl_xor(tmax, 32));
        if (__ballot(tmax > mrun + THR)) {      // defer-rescale: wave-uniform trigger
            float mnew = fmaxf(mrun, tmax);
            float scl = __expf(mrun - mnew);
            mrun = mnew;
            lrun *= scl;
            #pragma unroll
            for (int r = 0; r < 16; ++r) {
                float sr = __shfl(scl, (lane & 32) + ((r & 3) + 8 * (r >> 2) + 4 * lh2));
                #pragma unroll
                for (int cc = 0; cc < 4; ++cc) yacc[cc][r] *= sr;
            }
        }
        float rsum = 0.f;
        #pragma unroll
        for (int i = 0; i < 16; ++i) { S0[i] = __expf(S0[i] - mrun); rsum += S0[i]; }
        #pragma unroll
        for (int i = 0; i < 16; ++i) { S1[i] = __expf(S1[i] - mrun); rsum += S1[i]; }
        rsum += __shfl_xor(rsum, 32);
        lrun += rsum;

        // ---- P pack (f16 pairs) -> wave-private LDS (same-wave readback, no barrier)
        unsigned prow = pbb + (unsigned)l31 * 32;
        #pragma unroll
        for (int q = 0; q < 4; ++q) {
            uint2 w0; w0.x = pk2(S0[4*q], S0[4*q+1]); w0.y = pk2(S0[4*q+2], S0[4*q+3]);
            *(uint2*)&lds_u32[prow + (unsigned)((q * 4 + 2 * lh2) ^ xr)] = w0;
            uint2 w1; w1.x = pk2(S1[4*q], S1[4*q+1]); w1.y = pk2(S1[4*q+2], S1[4*q+3]);
            *(uint2*)&lds_u32[prow + (unsigned)((16 + q * 4 + 2 * lh2) ^ xr)] = w1;
        }

        // ---- y += P * g
        f16x8 a_p[4];
        #pragma unroll
        for (int kc = 0; kc < 4; ++kc)
            a_p[kc] = *(const f16x8*)&lds_u32[prow + (unsigned)((kc * 8 + lh2 * 4) ^ xr)];
        __builtin_amdgcn_s_setprio(1);
        #pragma unroll
        for (int cc = 0; cc < 4; ++cc) {
            #pragma unroll
            for (int kc = 0; kc < 4; ++kc) {
                f16x8 bg = *(const f16x8*)&lds_u32[gbb + (unsigned)(cc * 32 + l31) * 32
                                                  + (unsigned)((kc * 8 + lh2 * 4) ^ xr)];
                yacc[cc] = __builtin_amdgcn_mfma_f32_32x32x16_f16(a_p[kc], bg, yacc[cc], 0, 0, 0);
            }
        }
        __builtin_amdgcn_s_setprio(0);

        __syncthreads();                 // all waves done reading this step's tiles
        if (step < 7) {
            commit();                    // write prefetched tile into (same) buffers
            __syncthreads();
        }
    }

    // ---- in-block combine of the two m-halves (flash-decoding style)
    float* cf = (float*)lds_u32;
    if (s == 1) {
        if (lh2 == 0) {
            cf[8192 + h * 32 + l31] = mrun;
            cf[8256 + h * 32 + l31] = lrun;
        }
        #pragma unroll
        for (int r = 0; r < 16; ++r) {
            int ny = (r & 3) + 8 * (r >> 2) + 4 * lh2;
            #pragma unroll
            for (int cc = 0; cc < 4; ++cc)
                cf[h * 4096 + ny * 128 + cc * 32 + l31] = yacc[cc][r];
        }
    }
    __syncthreads();
    if (s == 0) {
        float m1 = cf[8192 + h * 32 + l31];
        float l1 = cf[8256 + h * 32 + l31];
        float M  = fmaxf(mrun, m1);
        float a  = __expf(mrun - M), bt = __expf(m1 - M);
        float L  = a * lrun + bt * l1;
        if (lh2 == 0) {
            cf[8320 + h * 32 + l31] = a / L;
            cf[8384 + h * 32 + l31] = bt / L;
        }
    }
    __syncthreads();
    if (s == 0) {
        #pragma unroll
        for (int r = 0; r < 16; ++r) {
            int ny = (r & 3) + 8 * (r >> 2) + 4 * lh2;
            float far = cf[8320 + h * 32 + ny];
            float fbr = cf[8384 + h * 32 + ny];
            unsigned short* yp = y + ((size_t)b * NN + row0 + h * 32 + ny) * CI + l31;
            #pragma unroll
            for (int cc = 0; cc < 4; ++cc) {
                float y1 = cf[h * 4096 + ny * 128 + cc * 32 + l31];
                yp[cc * 32] = f2h_bits(far * yacc[cc][r] + fbr * y1);
            }
        }
    }
}

// ---------------------------------------------------------------- K4: W conv (MFMA) -> f16 wy + BN partial sums
__global__ __launch_bounds__(256) void k_wconv(const unsigned short* __restrict__ y,
        const unsigned short* __restrict__ wwh, const float* __restrict__ wb,
        unsigned short* __restrict__ wyh, float* __restrict__ psum, float* __restrict__ psq) {
    int blk = blockIdx.x;                  // 512 blocks of 64 n
    int b   = blk >> 6;
    int nloc = (blk & 63) * 64;
    int tid = threadIdx.x;
    int lane = tid & 63, wv = tid >> 6;
    int lr = lane & 15, lh = lane >> 4;

    f32x4 acc[4][4];
    #pragma unroll
    for (int i = 0; i < 4; ++i)
        #pragma unroll
        for (int j = 0; j < 4; ++j) acc[i][j] = (f32x4){0.f, 0.f, 0.f, 0.f};

    const unsigned short* yb = y + ((size_t)b * NN + nloc) * CI;
    #pragma unroll
    for (int kc = 0; kc < 4; ++kc) {
        f16x8 a[4], bf[4];
        #pragma unroll
        for (int at = 0; at < 4; ++at)
            a[at] = *(const f16x8*)&wwh[(wv * 64 + at * 16 + lr) * CI + kc * 32 + lh * 8];
        #pragma unroll
        for (int bt = 0; bt < 4; ++bt)
            bf[bt] = *(const f16x8*)&yb[(size_t)(bt * 16 + lr) * CI + kc * 32 + lh * 8];
        #pragma unroll
        for (int at = 0; at < 4; ++at)
            #pragma unroll
            for (int bt = 0; bt < 4; ++bt)
                acc[at][bt] = __builtin_amdgcn_mfma_f32_16x16x32_f16(a[at], bf[bt], acc[at][bt], 0, 0, 0);
    }
    #pragma unroll
    for (int at = 0; at < 4; ++at) {
        #pragma unroll
        for (int r = 0; r < 4; ++r) {
            int co = wv * 64 + at * 16 + lh * 4 + r;
            float bias = wb[co];
            unsigned short* wp = wyh + ((size_t)b * C + co) * NN + nloc;
            float sv = 0.f, q = 0.f;
            #pragma unroll
            for (int bt = 0; bt < 4; ++bt) {
                float v = acc[at][bt][r] + bias;
                wp[bt * 16 + lr] = f2h_bits(v);
                sv += v;
                q = fmaf(v, v, q);
            }
            #pragma unroll
            for (int o = 1; o < 16; o <<= 1) {
                sv += __shfl_xor(sv, o);
                q  += __shfl_xor(q, o);
            }
            if (lr == 0) {
                psum[co * 512 + blk] = sv;
                psq[co * 512 + blk]  = q;
            }
        }
    }
}

// ---------------------------------------------------------------- K4b: reduce BN partials
__global__ __launch_bounds__(64) void k_stats_r(const float* __restrict__ psum,
        const float* __restrict__ psq, float* __restrict__ stats) {
    int c = blockIdx.x;
    int lane = threadIdx.x;
    float s = 0.f, q = 0.f;
    #pragma unroll
    for (int k = 0; k < 8; ++k) {
        s += psum[c * 512 + lane + k * 64];
        q += psq[c * 512 + lane + k * 64];
    }
    #pragma unroll
    for (int o = 32; o >= 1; o >>= 1) {
        s += __shfl_down(s, o);
        q += __shfl_down(q, o);
    }
    if (lane == 0) { stats[c] = s; stats[256 + c] = q; }
}

// ---------------------------------------------------------------- K5: BN apply + residual (f16 wy input)
__global__ __launch_bounds__(256) void k_bn_out(const unsigned short* __restrict__ wyh,
        const float* __restrict__ x, const float* __restrict__ stats,
        const float* __restrict__ gamma, const float* __restrict__ beta,
        float* __restrict__ out) {
    size_t t = (size_t)blockIdx.x * 256 + threadIdx.x;   // 8-element groups
    size_t base = t * 8;
    int c = (int)((base >> 12) & 255);
    float mean = stats[c] * (1.f / 32768.f);
    float var  = stats[256 + c] * (1.f / 32768.f) - mean * mean;
    float sc = gamma[c] * rsqrtf(var + EPS);
    float sh = beta[c] - mean * sc;
    ushort4 w0 = *(const ushort4*)&wyh[base];
    ushort4 w1 = *(const ushort4*)&wyh[base + 4];
    float4 x0 = *(const float4*)&x[base];
    float4 x1 = *(const float4*)&x[base + 4];
    float4 o0, o1;
    o0.x = fmaf(h2f(w0.x), sc, sh) + x0.x;
    o0.y = fmaf(h2f(w0.y), sc, sh) + x0.y;
    o0.z = fmaf(h2f(w0.z), sc, sh) + x0.z;
    o0.w = fmaf(h2f(w0.w), sc, sh) + x0.w;
    o1.x = fmaf(h2f(w1.x), sc, sh) + x1.x;
    o1.y = fmaf(h2f(w1.y), sc, sh) + x1.y;
    o1.z = fmaf(h2f(w1.z), sc, sh) + x1.z;
    o1.w = fmaf(h2f(w1.w), sc, sh) + x1.w;
    *(float4*)&out[base]     = o0;
    *(float4*)&out[base + 4] = o1;
}

// ----------------------------------------------------------------
extern "C" void kernel_launch(void* const* d_in, const int* in_sizes, int n_in,
                              void* d_out, int out_size, void* d_ws, size_t ws_size,
                              hipStream_t stream) {
    const float* x    = (const float*)d_in[0];
    const float* g_w  = (const float*)d_in[1];
    const float* g_b  = (const float*)d_in[2];
    const float* th_w = (const float*)d_in[3];
    const float* th_b = (const float*)d_in[4];
    const float* ph_w = (const float*)d_in[5];
    const float* ph_b = (const float*)d_in[6];
    const float* w_w  = (const float*)d_in[7];
    const float* w_b  = (const float*)d_in[8];
    const float* bn_g = (const float*)d_in[9];
    const float* bn_b = (const float*)d_in[10];
    float* out = (float*)d_out;

    char* w0 = (char*)d_ws;
    unsigned short* xh    = (unsigned short*)w0;                 // [B][N][C] f16   16,777,216 B
    unsigned short* theta = (unsigned short*)(w0 + 16777216);    // [B][N][CI] f16   8,388,608 B
    unsigned short* wh    = (unsigned short*)(w0 + 25165824);    // 4x32768 f16        262,144 B
    unsigned short* twh   = wh;
    unsigned short* pwh   = wh + 32768;
    unsigned short* gwh   = wh + 65536;
    unsigned short* wwh   = wh + 98304;
    unsigned short* phi   = (unsigned short*)(w0 + 25427968);    // [B][m][CI] f16   2,097,152 B
    unsigned short* gx    = (unsigned short*)(w0 + 27525120);    // [B][CI][m] f16   2,097,152 B
    unsigned short* yh    = (unsigned short*)(w0 + 29622272);    // [B][N][CI] f16   8,388,608 B
    unsigned short* wyh   = (unsigned short*)(w0 + 38010880);    // [B][C][N]  f16  16,777,216 B
    float*          psum  = (float*)(w0 + 54788096);             // [256][512] f32     524,288 B
    float*          psq   = (float*)(w0 + 55312384);             // [256][512] f32     524,288 B
    float*          stats = (float*)(w0 + 55836672);             // 512 f32

    k_xt<<<dim3(65, 4, B), 256, 0, stream>>>(x, xh, th_w, ph_w, g_w, w_w, wh);
    k_convs<<<256, 512, 0, stream>>>(xh, twh, pwh, gwh, th_b, ph_b, g_b, theta, phi, gx);
    k_attn_mfma<<<512, 256, 0, stream>>>(theta, phi, gx, yh);
    k_wconv<<<512, 256, 0, stream>>>(yh, wwh, w_b, wyh, psum, psq);
    k_stats_r<<<256, 64, 0, stream>>>(psum, psq, stats);
    k_bn_out<<<4096, 256, 0, stream>>>(wyh, x, stats, bn_g, bn_b, out);
}

// Round 9
// 181.861 us; speedup vs baseline: 1.1390x; 1.1390x over previous
//
#include <hip/hip_runtime.h>
#include <hip/hip_bf16.h>
#include <hip/hip_fp16.h>
#include <math.h>

#define B 8
#define C 256
#define HH 64
#define WW 64
#define NN 4096      // H*W
#define CI 128
#define NS 1024      // pooled spatial
#define EPS 1e-5f
#define THR 8.0f

typedef __attribute__((ext_vector_type(8))) _Float16 f16x8;
typedef __attribute__((ext_vector_type(4))) float f32x4;
typedef __attribute__((ext_vector_type(16))) float f32x16;

static __device__ __forceinline__ unsigned short f2h_bits(float f) {
    return __half_as_ushort(__float2half(f));   // v_cvt_f16_f32 (RNE)
}
static __device__ __forceinline__ float h2f(unsigned short u) {
    return __half2float(__ushort_as_half(u));
}
static __device__ __forceinline__ unsigned pk2(float a, float b) {
    typedef __fp16 fp16x2_t __attribute__((ext_vector_type(2)));
    union { fp16x2_t h; unsigned u; } cv;
    cv.h = __builtin_amdgcn_cvt_pkrtz(a, b);
    return cv.u;
}

// ---------------------------------------------------------------- K0: x transpose->f16 (+ weight prep folded in)
__global__ __launch_bounds__(256) void k_xt(const float* __restrict__ x,
        unsigned short* __restrict__ xh,
        const float* __restrict__ tw, const float* __restrict__ pw,
        const float* __restrict__ gw, const float* __restrict__ ww,
        unsigned short* __restrict__ wh) {
    int tid = threadIdx.x;
    if (blockIdx.x == 64) {   // weight prep: 32 instances x 4096 elements
        int inst = blockIdx.y * B + blockIdx.z;       // 0..31
        int base = inst * 4096;
        #pragma unroll
        for (int k = 0; k < 16; ++k) {
            int idx = base + tid + k * 256;           // 0..131071
            int sel = idx >> 15, off = idx & 32767;
            const float* src = (sel == 0) ? tw : (sel == 1) ? pw : (sel == 2) ? gw : ww;
            wh[idx] = f2h_bits(src[off]);
        }
        return;
    }
    __shared__ float s_t[64 * 65];
    int n0 = blockIdx.x * 64;
    int c0 = blockIdx.y * 64;
    int b  = blockIdx.z;
    #pragma unroll
    for (int k = 0; k < 16; ++k) {
        int idx = tid + k * 256;           // 0..4095
        int cl = idx >> 6, nl = idx & 63;
        s_t[cl * 65 + nl] = x[((size_t)b * C + c0 + cl) * NN + n0 + nl];
    }
    __syncthreads();
    #pragma unroll
    for (int k = 0; k < 8; ++k) {
        int idx = tid + k * 256;           // 0..2047
        int nl = idx >> 5, cp = (idx & 31) * 2;
        ushort2 o;
        o.x = f2h_bits(s_t[cp * 65 + nl]);
        o.y = f2h_bits(s_t[(cp + 1) * 65 + nl]);
        *(ushort2*)&xh[((size_t)b * NN + n0 + nl) * C + c0 + cp] = o;
    }
}

// ---------------------------------------------------------------- K1: fused theta + pooled phi/g convs (MFMA)
__global__ __launch_bounds__(512) void k_convs(const unsigned short* __restrict__ xh,
        const unsigned short* __restrict__ twh, const unsigned short* __restrict__ pwh,
        const unsigned short* __restrict__ gwh,
        const float* __restrict__ tb, const float* __restrict__ pb, const float* __restrict__ gb_,
        unsigned short* __restrict__ theta, unsigned short* __restrict__ phi,
        unsigned short* __restrict__ gout) {
    int blk = blockIdx.x;                 // 256 blocks
    int b   = blk >> 5;
    int mh  = blk & 31;                   // pooled h row
    int tid = threadIdx.x;
    int lane = tid & 63, wv = tid >> 6;
    int lr = lane & 15, lh = lane >> 4;
    int wn = wv & 3, wc = wv >> 2;
    size_t row0 = (size_t)blk * 128;

    f32x4 accT[8];
    f32x4 aP0[4], aP1[4], aG0[4], aG1[4];
    #pragma unroll
    for (int i = 0; i < 8; ++i) accT[i] = (f32x4){0,0,0,0};
    #pragma unroll
    for (int i = 0; i < 4; ++i) {
        aP0[i] = (f32x4){0,0,0,0}; aP1[i] = (f32x4){0,0,0,0};
        aG0[i] = (f32x4){0,0,0,0}; aG1[i] = (f32x4){0,0,0,0};
    }

    const unsigned short* ap0 = xh + (row0 + wn * 16 + lr) * C + lh * 8;
    const unsigned short* ap1 = ap0 + (size_t)64 * C;
    #pragma unroll
    for (int kc = 0; kc < 8; ++kc) {
        f16x8 a0 = *(const f16x8*)(ap0 + kc * 32);
        f16x8 a1 = *(const f16x8*)(ap1 + kc * 32);
        f16x8 aT = (wv < 4) ? a0 : a1;
        #pragma unroll
        for (int ct = 0; ct < 8; ++ct) {
            f16x8 bt_ = *(const f16x8*)&twh[(ct * 16 + lr) * C + kc * 32 + lh * 8];
            accT[ct] = __builtin_amdgcn_mfma_f32_16x16x32_f16(aT, bt_, accT[ct], 0, 0, 0);
        }
        #pragma unroll
        for (int ct = 0; ct < 4; ++ct) {
            int wrow = (wc * 64 + ct * 16 + lr) * C + kc * 32 + lh * 8;
            f16x8 bp = *(const f16x8*)&pwh[wrow];
            f16x8 bg = *(const f16x8*)&gwh[wrow];
            aP0[ct] = __builtin_amdgcn_mfma_f32_16x16x32_f16(a0, bp, aP0[ct], 0, 0, 0);
            aP1[ct] = __builtin_amdgcn_mfma_f32_16x16x32_f16(a1, bp, aP1[ct], 0, 0, 0);
            aG0[ct] = __builtin_amdgcn_mfma_f32_16x16x32_f16(a0, bg, aG0[ct], 0, 0, 0);
            aG1[ct] = __builtin_amdgcn_mfma_f32_16x16x32_f16(a1, bg, aG1[ct], 0, 0, 0);
        }
    }
    #pragma unroll
    for (int ct = 0; ct < 8; ++ct) {
        int ci = ct * 16 + lr;
        float bias = tb[ci];
        #pragma unroll
        for (int r = 0; r < 4; ++r)
            theta[(row0 + wv * 16 + lh * 4 + r) * CI + ci] = f2h_bits(accT[ct][r] + bias);
    }
    #pragma unroll
    for (int ct = 0; ct < 4; ++ct) {
        int ci = wc * 64 + ct * 16 + lr;
        float biasP = pb[ci], biasG = gb_[ci];
        #pragma unroll
        for (int j = 0; j < 2; ++j) {
            int m = mh * 32 + wn * 8 + lh * 2 + j;
            float vP = fmaxf(fmaxf(aP0[ct][2*j], aP0[ct][2*j+1]),
                             fmaxf(aP1[ct][2*j], aP1[ct][2*j+1])) + biasP;
            float vG = fmaxf(fmaxf(aG0[ct][2*j], aG0[ct][2*j+1]),
                             fmaxf(aG1[ct][2*j], aG1[ct][2*j+1])) + biasG;
            phi[((size_t)b * NS + m) * CI + ci]  = f2h_bits(vP);
            gout[((size_t)b * CI + ci) * NS + m] = f2h_bits(vG);
        }
    }
}

// ---------------------------------------------------------------- K3: fused attention v3
// 32x32x16 MFMA, swapped QK (A=phi, B=theta) -> in-register softmax; m-split x2 in block;
// XOR-swizzled zero-pad LDS; defer-rescale THR=8; in-block flash combine.
// __launch_bounds__(256,2): LDS caps us at 2 blocks/CU anyway -> allow 256 VGPRs, no spill.
// theta [b][n][ci] f16, phi [b][m][ci] f16, g [b][ci][m] f16 -> y [b][n][ci] f16
__global__ __launch_bounds__(256, 2) void k_attn_mfma(const unsigned short* __restrict__ theta,
        const unsigned short* __restrict__ phi, const unsigned short* __restrict__ g,
        unsigned short* __restrict__ y) {
    __shared__ unsigned lds_u32[20480];   // 81920 B exactly -> 2 blocks/CU
    int bid = blockIdx.x;                  // 512
    int b   = bid & 7;                     // batch -> XCD (round-robin heuristic)
    int rb  = bid >> 3;                    // 0..63
    int tid = threadIdx.x;
    int lane = tid & 63;
    int wv  = tid >> 6;
    int h   = wv & 1;                      // n-half (32 rows)
    int s   = wv >> 1;                     // m-half (8 tiles)
    int l31 = lane & 31;
    int lh2 = lane >> 5;                   // 0/1 (k-group)
    int xr  = (lane & 7) << 2;             // XOR swizzle (dwords)
    int row0 = rb * 64;

    const unsigned phb = s * 4096;           // phi stream base (dwords): 64 rows x 64 dw
    const unsigned gbb = 8192 + s * 4096;    // g stream base: 128 rows x 32 dw
    const unsigned pbb = 16384 + wv * 1024;  // P wave base: 32 rows x 32 dw

    // theta B-frags (col n = l31, k = lh2*8+j), held whole kernel
    f16x8 b_th[8];
    {
        const unsigned short* tp = theta + ((size_t)b * NN + row0 + h * 32 + l31) * CI + lh2 * 8;
        #pragma unroll
        for (int kc = 0; kc < 8; ++kc)
            b_th[kc] = *(const f16x8*)(tp + kc * 16);
    }

    const unsigned short* phsrc = phi + (size_t)b * NS * CI;
    const unsigned short* gsrc  = g + (size_t)b * CI * NS;
    int tl = tid & 127;                    // thread-in-stream

    uint4 rph[8], rg[8];
    auto issue = [&](int mt) {
        #pragma unroll
        for (int k = 0; k < 8; ++k) {
            int rowm = k * 8 + (tl >> 4);
            rph[k] = *(const uint4*)(phsrc + (size_t)(mt * 64 + rowm) * CI + (tl & 15) * 8);
            int ci = k * 16 + (tl >> 3);
            rg[k]  = *(const uint4*)(gsrc + (size_t)ci * NS + mt * 64 + (tl & 7) * 8);
        }
    };
    auto commit = [&]() {
        #pragma unroll
        for (int k = 0; k < 8; ++k) {
            int rowm = k * 8 + (tl >> 4);
            *(uint4*)&lds_u32[phb + rowm * 64 + (((tl & 15) * 4) ^ ((rowm & 7) << 2))] = rph[k];
            int ci = k * 16 + (tl >> 3);
            *(uint4*)&lds_u32[gbb + ci * 32 + (((tl & 7) * 4) ^ ((ci & 7) << 2))] = rg[k];
        }
    };

    f32x16 yacc[4];
    #pragma unroll
    for (int cc = 0; cc < 4; ++cc)
        #pragma unroll
        for (int i = 0; i < 16; ++i) yacc[cc][i] = 0.f;
    float mrun = -1e30f, lrun = 0.f;

    issue(s * 8);
    commit();
    __syncthreads();

    for (int step = 0; step < 8; ++step) {
        if (step < 7) issue(s * 8 + step + 1);

        // ---- S^T = phi * theta^T : lane holds 32 m-values for ONE n = l31
        f32x16 S0, S1;
        #pragma unroll
        for (int i = 0; i < 16; ++i) { S0[i] = 0.f; S1[i] = 0.f; }
        __builtin_amdgcn_s_setprio(1);
        #pragma unroll
        for (int kc = 0; kc < 8; ++kc) {
            unsigned dc = (unsigned)((kc * 8 + lh2 * 4) ^ xr);
            f16x8 a0 = *(const f16x8*)&lds_u32[phb + l31 * 64 + dc];
            f16x8 a1 = *(const f16x8*)&lds_u32[phb + (32 + l31) * 64 + dc];
            S0 = __builtin_amdgcn_mfma_f32_32x32x16_f16(a0, b_th[kc], S0, 0, 0, 0);
            S1 = __builtin_amdgcn_mfma_f32_32x32x16_f16(a1, b_th[kc], S1, 0, 0, 0);
        }
        __builtin_amdgcn_s_setprio(0);

        // ---- softmax: in-register over 32 values + one cross-half shuffle
        float tmax = S0[0];
        #pragma unroll
        for (int i = 1; i < 16; ++i) tmax = fmaxf(tmax, S0[i]);
        #pragma unroll
        for (int i = 0; i < 16; ++i) tmax = fmaxf(tmax, S1[i]);
        tmax = fmaxf(tmax, __shfl_xor(tmax, 32));
        if (__ballot(tmax > mrun + THR)) {      // defer-rescale: wave-uniform trigger
            float mnew = fmaxf(mrun, tmax);
            float scl = __expf(mrun - mnew);
            mrun = mnew;
            lrun *= scl;
            #pragma unroll
            for (int r = 0; r < 16; ++r) {
                float sr = __shfl(scl, (lane & 32) + ((r & 3) + 8 * (r >> 2) + 4 * lh2));
                #pragma unroll
                for (int cc = 0; cc < 4; ++cc) yacc[cc][r] *= sr;
            }
        }
        float rsum = 0.f;
        #pragma unroll
        for (int i = 0; i < 16; ++i) { S0[i] = __expf(S0[i] - mrun); rsum += S0[i]; }
        #pragma unroll
        for (int i = 0; i < 16; ++i) { S1[i] = __expf(S1[i] - mrun); rsum += S1[i]; }
        rsum += __shfl_xor(rsum, 32);
        lrun += rsum;

        // ---- P pack (f16 pairs) -> wave-private LDS (same-wave readback, no barrier)
        unsigned prow = pbb + (unsigned)l31 * 32;
        #pragma unroll
        for (int q = 0; q < 4; ++q) {
            uint2 w0; w0.x = pk2(S0[4*q], S0[4*q+1]); w0.y = pk2(S0[4*q+2], S0[4*q+3]);
            *(uint2*)&lds_u32[prow + (unsigned)((q * 4 + 2 * lh2) ^ xr)] = w0;
            uint2 w1; w1.x = pk2(S1[4*q], S1[4*q+1]); w1.y = pk2(S1[4*q+2], S1[4*q+3]);
            *(uint2*)&lds_u32[prow + (unsigned)((16 + q * 4 + 2 * lh2) ^ xr)] = w1;
        }

        // ---- y += P * g
        f16x8 a_p[4];
        #pragma unroll
        for (int kc = 0; kc < 4; ++kc)
            a_p[kc] = *(const f16x8*)&lds_u32[prow + (unsigned)((kc * 8 + lh2 * 4) ^ xr)];
        __builtin_amdgcn_s_setprio(1);
        #pragma unroll
        for (int cc = 0; cc < 4; ++cc) {
            #pragma unroll
            for (int kc = 0; kc < 4; ++kc) {
                f16x8 bg = *(const f16x8*)&lds_u32[gbb + (unsigned)(cc * 32 + l31) * 32
                                                  + (unsigned)((kc * 8 + lh2 * 4) ^ xr)];
                yacc[cc] = __builtin_amdgcn_mfma_f32_32x32x16_f16(a_p[kc], bg, yacc[cc], 0, 0, 0);
            }
        }
        __builtin_amdgcn_s_setprio(0);

        __syncthreads();                 // all waves done reading this step's tiles
        if (step < 7) {
            commit();                    // write prefetched tile into (same) buffers
            __syncthreads();
        }
    }

    // ---- in-block combine of the two m-halves (flash-decoding style)
    float* cf = (float*)lds_u32;
    if (s == 1) {
        if (lh2 == 0) {
            cf[8192 + h * 32 + l31] = mrun;
            cf[8256 + h * 32 + l31] = lrun;
        }
        #pragma unroll
        for (int r = 0; r < 16; ++r) {
            int ny = (r & 3) + 8 * (r >> 2) + 4 * lh2;
            #pragma unroll
            for (int cc = 0; cc < 4; ++cc)
                cf[h * 4096 + ny * 128 + cc * 32 + l31] = yacc[cc][r];
        }
    }
    __syncthreads();
    if (s == 0) {
        float m1 = cf[8192 + h * 32 + l31];
        float l1 = cf[8256 + h * 32 + l31];
        float M  = fmaxf(mrun, m1);
        float a  = __expf(mrun - M), bt = __expf(m1 - M);
        float L  = a * lrun + bt * l1;
        if (lh2 == 0) {
            cf[8320 + h * 32 + l31] = a / L;
            cf[8384 + h * 32 + l31] = bt / L;
        }
    }
    __syncthreads();
    if (s == 0) {
        #pragma unroll
        for (int r = 0; r < 16; ++r) {
            int ny = (r & 3) + 8 * (r >> 2) + 4 * lh2;
            float far = cf[8320 + h * 32 + ny];
            float fbr = cf[8384 + h * 32 + ny];
            unsigned short* yp = y + ((size_t)b * NN + row0 + h * 32 + ny) * CI + l31;
            #pragma unroll
            for (int cc = 0; cc < 4; ++cc) {
                float y1 = cf[h * 4096 + ny * 128 + cc * 32 + l31];
                yp[cc * 32] = f2h_bits(far * yacc[cc][r] + fbr * y1);
            }
        }
    }
}

// ---------------------------------------------------------------- K4: W conv (MFMA) -> f16 wy + BN partial sums
__global__ __launch_bounds__(256) void k_wconv(const unsigned short* __restrict__ y,
        const unsigned short* __restrict__ wwh, const float* __restrict__ wb,
        unsigned short* __restrict__ wyh, float* __restrict__ psum, float* __restrict__ psq) {
    int blk = blockIdx.x;                  // 512 blocks of 64 n
    int b   = blk >> 6;
    int nloc = (blk & 63) * 64;
    int tid = threadIdx.x;
    int lane = tid & 63, wv = tid >> 6;
    int lr = lane & 15, lh = lane >> 4;

    f32x4 acc[4][4];
    #pragma unroll
    for (int i = 0; i < 4; ++i)
        #pragma unroll
        for (int j = 0; j < 4; ++j) acc[i][j] = (f32x4){0.f, 0.f, 0.f, 0.f};

    const unsigned short* yb = y + ((size_t)b * NN + nloc) * CI;
    #pragma unroll
    for (int kc = 0; kc < 4; ++kc) {
        f16x8 a[4], bf[4];
        #pragma unroll
        for (int at = 0; at < 4; ++at)
            a[at] = *(const f16x8*)&wwh[(wv * 64 + at * 16 + lr) * CI + kc * 32 + lh * 8];
        #pragma unroll
        for (int bt = 0; bt < 4; ++bt)
            bf[bt] = *(const f16x8*)&yb[(size_t)(bt * 16 + lr) * CI + kc * 32 + lh * 8];
        #pragma unroll
        for (int at = 0; at < 4; ++at)
            #pragma unroll
            for (int bt = 0; bt < 4; ++bt)
                acc[at][bt] = __builtin_amdgcn_mfma_f32_16x16x32_f16(a[at], bf[bt], acc[at][bt], 0, 0, 0);
    }
    #pragma unroll
    for (int at = 0; at < 4; ++at) {
        #pragma unroll
        for (int r = 0; r < 4; ++r) {
            int co = wv * 64 + at * 16 + lh * 4 + r;
            float bias = wb[co];
            unsigned short* wp = wyh + ((size_t)b * C + co) * NN + nloc;
            float sv = 0.f, q = 0.f;
            #pragma unroll
            for (int bt = 0; bt < 4; ++bt) {
                float v = acc[at][bt][r] + bias;
                wp[bt * 16 + lr] = f2h_bits(v);
                sv += v;
                q = fmaf(v, v, q);
            }
            #pragma unroll
            for (int o = 1; o < 16; o <<= 1) {
                sv += __shfl_xor(sv, o);
                q  += __shfl_xor(q, o);
            }
            if (lr == 0) {
                psum[co * 512 + blk] = sv;
                psq[co * 512 + blk]  = q;
            }
        }
    }
}

// ---------------------------------------------------------------- K4b: reduce BN partials
__global__ __launch_bounds__(64) void k_stats_r(const float* __restrict__ psum,
        const float* __restrict__ psq, float* __restrict__ stats) {
    int c = blockIdx.x;
    int lane = threadIdx.x;
    float s = 0.f, q = 0.f;
    #pragma unroll
    for (int k = 0; k < 8; ++k) {
        s += psum[c * 512 + lane + k * 64];
        q += psq[c * 512 + lane + k * 64];
    }
    #pragma unroll
    for (int o = 32; o >= 1; o >>= 1) {
        s += __shfl_down(s, o);
        q += __shfl_down(q, o);
    }
    if (lane == 0) { stats[c] = s; stats[256 + c] = q; }
}

// ---------------------------------------------------------------- K5: BN apply + residual (f16 wy input)
__global__ __launch_bounds__(256) void k_bn_out(const unsigned short* __restrict__ wyh,
        const float* __restrict__ x, const float* __restrict__ stats,
        const float* __restrict__ gamma, const float* __restrict__ beta,
        float* __restrict__ out) {
    size_t t = (size_t)blockIdx.x * 256 + threadIdx.x;   // 8-element groups
    size_t base = t * 8;
    int c = (int)((base >> 12) & 255);
    float mean = stats[c] * (1.f / 32768.f);
    float var  = stats[256 + c] * (1.f / 32768.f) - mean * mean;
    float sc = gamma[c] * rsqrtf(var + EPS);
    float sh = beta[c] - mean * sc;
    ushort4 w0 = *(const ushort4*)&wyh[base];
    ushort4 w1 = *(const ushort4*)&wyh[base + 4];
    float4 x0 = *(const float4*)&x[base];
    float4 x1 = *(const float4*)&x[base + 4];
    float4 o0, o1;
    o0.x = fmaf(h2f(w0.x), sc, sh) + x0.x;
    o0.y = fmaf(h2f(w0.y), sc, sh) + x0.y;
    o0.z = fmaf(h2f(w0.z), sc, sh) + x0.z;
    o0.w = fmaf(h2f(w0.w), sc, sh) + x0.w;
    o1.x = fmaf(h2f(w1.x), sc, sh) + x1.x;
    o1.y = fmaf(h2f(w1.y), sc, sh) + x1.y;
    o1.z = fmaf(h2f(w1.z), sc, sh) + x1.z;
    o1.w = fmaf(h2f(w1.w), sc, sh) + x1.w;
    *(float4*)&out[base]     = o0;
    *(float4*)&out[base + 4] = o1;
}

// ----------------------------------------------------------------
extern "C" void kernel_launch(void* const* d_in, const int* in_sizes, int n_in,
                              void* d_out, int out_size, void* d_ws, size_t ws_size,
                              hipStream_t stream) {
    const float* x    = (const float*)d_in[0];
    const float* g_w  = (const float*)d_in[1];
    const float* g_b  = (const float*)d_in[2];
    const float* th_w = (const float*)d_in[3];
    const float* th_b = (const float*)d_in[4];
    const float* ph_w = (const float*)d_in[5];
    const float* ph_b = (const float*)d_in[6];
    const float* w_w  = (const float*)d_in[7];
    const float* w_b  = (const float*)d_in[8];
    const float* bn_g = (const float*)d_in[9];
    const float* bn_b = (const float*)d_in[10];
    float* out = (float*)d_out;

    char* w0 = (char*)d_ws;
    unsigned short* xh    = (unsigned short*)w0;                 // [B][N][C] f16   16,777,216 B
    unsigned short* theta = (unsigned short*)(w0 + 16777216);    // [B][N][CI] f16   8,388,608 B
    unsigned short* wh    = (unsigned short*)(w0 + 25165824);    // 4x32768 f16        262,144 B
    unsigned short* twh   = wh;
    unsigned short* pwh   = wh + 32768;
    unsigned short* gwh   = wh + 65536;
    unsigned short* wwh   = wh + 98304;
    unsigned short* phi   = (unsigned short*)(w0 + 25427968);    // [B][m][CI] f16   2,097,152 B
    unsigned short* gx    = (unsigned short*)(w0 + 27525120);    // [B][CI][m] f16   2,097,152 B
    unsigned short* yh    = (unsigned short*)(w0 + 29622272);    // [B][N][CI] f16   8,388,608 B
    unsigned short* wyh   = (unsigned short*)(w0 + 38010880);    // [B][C][N]  f16  16,777,216 B
    float*          psum  = (float*)(w0 + 54788096);             // [256][512] f32     524,288 B
    float*          psq   = (float*)(w0 + 55312384);             // [256][512] f32     524,288 B
    float*          stats = (float*)(w0 + 55836672);             // 512 f32

    k_xt<<<dim3(65, 4, B), 256, 0, stream>>>(x, xh, th_w, ph_w, g_w, w_w, wh);
    k_convs<<<256, 512, 0, stream>>>(xh, twh, pwh, gwh, th_b, ph_b, g_b, theta, phi, gx);
    k_attn_mfma<<<512, 256, 0, stream>>>(theta, phi, gx, yh);
    k_wconv<<<512, 256, 0, stream>>>(yh, wwh, w_b, wyh, psum, psq);
    k_stats_r<<<256, 64, 0, stream>>>(psum, psq, stats);
    k_bn_out<<<4096, 256, 0, stream>>>(wyh, x, stats, bn_g, bn_b, out);
}